// Round 10
// baseline (344.806 us; speedup 1.0000x reference)
//
#include <hip/hip_runtime.h>

#define N_FEAT 128
#define F1 16
#define FH 8
#define F2 2
#define XPAD 132
#define NPB 512          // nodes per bucket (power of two)
#define NPB_SHIFT 9
#define BMAX 256         // max buckets -> supports N <= 131072
#define CHUNK 8192       // edges per binning block
#define HBLK 1024        // blocks for histogram kernel
#define K2 4             // slices per bucket for degree/scatter

// ---- nontemporal helpers (builtin requires native/ext_vector types) ----
typedef int   ev_i4 __attribute__((ext_vector_type(4)));
typedef float ev_f4 __attribute__((ext_vector_type(4)));

__device__ __forceinline__ int4 nt_load_i4(const void* p) {
    ev_i4 v = __builtin_nontemporal_load((const ev_i4*)p);
    return make_int4(v.x, v.y, v.z, v.w);
}
__device__ __forceinline__ int nt_load_i(const int* p) {
    return __builtin_nontemporal_load(p);
}
__device__ __forceinline__ float4 nt_load_f4(const void* p) {
    ev_f4 v = __builtin_nontemporal_load((const ev_f4*)p);
    return make_float4(v.x, v.y, v.z, v.w);
}

// ---------------- bucket histogram only ----------------
__global__ __launch_bounds__(256) void hist_kernel(const int* __restrict__ col, int E,
        int* __restrict__ bcnt) {
    __shared__ int hist[BMAX];
    int t = threadIdx.x;
    hist[t] = 0;
    __syncthreads();
    int nq = (E + 3) >> 2;
    for (int q = blockIdx.x * 256 + t; q < nq; q += HBLK * 256) {
        int e0 = q * 4;
        if (e0 + 3 < E) {
            int4 c = nt_load_i4(col + e0);
            atomicAdd(&hist[c.x >> NPB_SHIFT], 1);
            atomicAdd(&hist[c.y >> NPB_SHIFT], 1);
            atomicAdd(&hist[c.z >> NPB_SHIFT], 1);
            atomicAdd(&hist[c.w >> NPB_SHIFT], 1);
        } else {
            for (int e = e0; e < E; ++e) atomicAdd(&hist[col[e] >> NPB_SHIFT], 1);
        }
    }
    __syncthreads();
    if (hist[t]) atomicAdd(&bcnt[t], hist[t]);
}

// ---------------- exclusive scan of bucket counts (single block) ----------------
__global__ __launch_bounds__(256) void bscan_kernel(const int* __restrict__ bcnt,
        int* __restrict__ bstart, int* __restrict__ gcur, int E, int nbuck) {
    __shared__ int s[BMAX];
    int t = threadIdx.x;
    int v = (t < nbuck) ? bcnt[t] : 0;
    s[t] = v;
    __syncthreads();
    for (int off = 1; off < BMAX; off <<= 1) {
        int a = (t >= off) ? s[t - off] : 0;
        __syncthreads();
        s[t] += a;
        __syncthreads();
    }
    int excl = s[t] - v;
    if (t < nbuck) { bstart[t] = excl; gcur[t] = excl; }
    if (t == 0) bstart[nbuck] = E;
}

// ---------------- bin edges into buckets, LDS-staged ----------------
// ebin word = (src << NPB_SHIFT) | (dst & (NPB-1)), grouped by bucket = dst >> NPB_SHIFT
__global__ __launch_bounds__(256) void bin_kernel(const int* __restrict__ rowi,
        const int* __restrict__ coli, int* __restrict__ gcur,
        int* __restrict__ ebin, int E) {
    __shared__ int stage[CHUNK];
    __shared__ unsigned char sbkt[CHUNK];
    __shared__ int cnt[BMAX];
    __shared__ int pos[BMAX];
    __shared__ int runb[BMAX];
    int t = threadIdx.x;
    int base = blockIdx.x * CHUNK;
    int nval = E - base; if (nval > CHUNK) nval = CHUNK;
    cnt[t] = 0;
    __syncthreads();

    int cbuf[32];
#pragma unroll
    for (int j = 0; j < 8; ++j) {
        int idx = base + ((j << 8) + t) * 4;
        if (idx + 3 < E) {
            int4 c4 = nt_load_i4(coli + idx);
            cbuf[j * 4 + 0] = c4.x; cbuf[j * 4 + 1] = c4.y;
            cbuf[j * 4 + 2] = c4.z; cbuf[j * 4 + 3] = c4.w;
        } else {
#pragma unroll
            for (int u = 0; u < 4; ++u) {
                int i2 = idx + u;
                cbuf[j * 4 + u] = (i2 < E) ? coli[i2] : -1;
            }
        }
    }
#pragma unroll
    for (int k = 0; k < 32; ++k)
        if (cbuf[k] >= 0) atomicAdd(&cnt[cbuf[k] >> NPB_SHIFT], 1);
    __syncthreads();

    pos[t] = cnt[t];
    __syncthreads();
    for (int off = 1; off < BMAX; off <<= 1) {
        int a = (t >= off) ? pos[t - off] : 0;
        __syncthreads();
        pos[t] += a;
        __syncthreads();
    }
    int myc = cnt[t];
    int excl = pos[t] - myc;
    if (myc > 0) {
        int g = atomicAdd(&gcur[t], myc);
        runb[t] = g - excl;
    }
    __syncthreads();
    cnt[t] = excl;
    __syncthreads();

#pragma unroll
    for (int j = 0; j < 8; ++j) {
        int idx = base + ((j << 8) + t) * 4;
        int rr[4];
        if (idx + 3 < E) {
            int4 r4 = nt_load_i4(rowi + idx);
            rr[0] = r4.x; rr[1] = r4.y; rr[2] = r4.z; rr[3] = r4.w;
        } else {
#pragma unroll
            for (int u = 0; u < 4; ++u) {
                int i2 = idx + u;
                rr[u] = (i2 < E) ? rowi[i2] : 0;
            }
        }
#pragma unroll
        for (int u = 0; u < 4; ++u) {
            int c = cbuf[j * 4 + u];
            if (c >= 0) {
                int b = c >> NPB_SHIFT;
                int lp = atomicAdd(&cnt[b], 1);
                stage[lp] = (rr[u] << NPB_SHIFT) | (c & (NPB - 1));
                sbkt[lp] = (unsigned char)b;
            }
        }
    }
    __syncthreads();
    // bucket-sorted, lane-consecutive write-out (plain stores: L2 write-combines)
    for (int i = t; i < nval; i += 256)
        ebin[runb[sbkt[i]] + i] = stage[i];
}

// ---------------- per-node degree from binned edges (split-K, 784 blocks) ----------------
__global__ __launch_bounds__(256) void degpart_kernel(const int* __restrict__ bstart,
        const int* __restrict__ ebin, int* __restrict__ degp) {
    __shared__ int cnt[NPB];
    int t = threadIdx.x;
    int bid = blockIdx.x;
    int b = bid / K2, slice = bid - b * K2;
    cnt[t] = 0; cnt[t + 256] = 0;
    __syncthreads();
    int s = bstart[b], e = bstart[b + 1];
    int per = (e - s + K2 - 1) / K2;
    int s0 = s + slice * per;
    int e0 = s0 + per; if (e0 > e) e0 = e;
    for (int i = s0 + t; i < e0; i += 1024) {
        int w[4];
#pragma unroll
        for (int u = 0; u < 4; ++u) {
            int idx = i + u * 256;
            w[u] = (idx < e0) ? nt_load_i(&ebin[idx]) : -1;
        }
#pragma unroll
        for (int u = 0; u < 4; ++u)
            if (w[u] >= 0) atomicAdd(&cnt[w[u] & (NPB - 1)], 1);
    }
    __syncthreads();
    int* dp = degp + (size_t)bid * NPB;
    dp[t] = cnt[t];
    dp[t + 256] = cnt[t + 256];
}

// ------- per-bucket: sum degree slices, LDS scan -> CSR row_start, dinv -------
__global__ __launch_bounds__(256) void rowscan_kernel(const int* __restrict__ bstart,
        const int* __restrict__ degp, int* __restrict__ rstart,
        float* __restrict__ dinv, int N, int E) {
    __shared__ int sd[NPB];
    int b = blockIdx.x, t = threadIdx.x;
    int base = b << NPB_SHIFT;
    int d0 = 0, d1 = 0;
    for (int sl = 0; sl < K2; ++sl) {
        const int* dp = degp + (size_t)(b * K2 + sl) * NPB;
        d0 += dp[t]; d1 += dp[t + 256];
    }
    sd[t] = d0; sd[t + 256] = d1;
    __syncthreads();
    for (int off = 1; off < NPB; off <<= 1) {
        int a0 = (t >= off) ? sd[t - off] : 0;
        int a1 = (t + 256 >= off) ? sd[t + 256 - off] : 0;
        __syncthreads();
        sd[t] += a0; sd[t + 256] += a1;
        __syncthreads();
    }
    int bs = bstart[b];
    int g0 = base + t, g1 = base + t + 256;
    if (g0 < N) { rstart[g0] = bs + sd[t] - d0;        dinv[g0] = rsqrtf((float)(d0 + 1)); }
    if (g1 < N) { rstart[g1] = bs + sd[t + 256] - d1;  dinv[g1] = rsqrtf((float)(d1 + 1)); }
    if (b == 0 && t == 0) rstart[N] = E;
}

// ------- split-K CSR scatter with per-slice cursor bases (plain stores) -------
__global__ __launch_bounds__(256) void csrscat_kernel(const int* __restrict__ bstart,
        const int* __restrict__ rstart, const int* __restrict__ degp,
        const int* __restrict__ ebin, int* __restrict__ csr, int N) {
    __shared__ int cur[NPB];
    int t = threadIdx.x;
    int bid = blockIdx.x;
    int b = bid / K2, slice = bid - b * K2;
    int base = b << NPB_SHIFT;
    for (int n = t; n < NPB; n += 256) {
        int g = base + n;
        int c = (g < N) ? rstart[g] : 0;
        for (int j = 0; j < slice; ++j)
            c += degp[(size_t)(b * K2 + j) * NPB + n];
        cur[n] = c;
    }
    __syncthreads();
    int s = bstart[b], e = bstart[b + 1];
    int per = (e - s + K2 - 1) / K2;
    int s0 = s + slice * per;
    int e0 = s0 + per; if (e0 > e) e0 = e;
    for (int i = s0 + t; i < e0; i += 1024) {
        int w[4];
#pragma unroll
        for (int u = 0; u < 4; ++u) {
            int idx = i + u * 256;
            w[u] = (idx < e0) ? nt_load_i(&ebin[idx]) : -1;
        }
#pragma unroll
        for (int u = 0; u < 4; ++u) {
            if (w[u] >= 0) {
                int p = atomicAdd(&cur[w[u] & (NPB - 1)], 1);
                csr[p] = w[u] >> NPB_SHIFT;
            }
        }
    }
}

// ---------------- layer-1 GEMM -> split halves hsA/hsB ----------------
__global__ __launch_bounds__(256) void gemm1_kernel(
    const float* __restrict__ x, const float* __restrict__ W1,
    const float* __restrict__ dinv, float* __restrict__ hsA,
    float* __restrict__ hsB, int N) {
    __shared__ __align__(16) float wsT[F1][XPAD];   // wsT[f][k] = W1[k][f]
    __shared__ __align__(16) float xs[16][XPAD];
    int t = threadIdx.x;
    for (int i = t; i < N_FEAT * F1; i += 256) {
        int k = i >> 4, f = i & 15;
        wsT[f][k] = W1[i];
    }
    int row0 = blockIdx.x * 16;
    for (int i = t; i < 16 * (N_FEAT / 4); i += 256) {
        int r = i >> 5, k4 = i & 31;
        int row = row0 + r;
        float4 v = (row < N) ? nt_load_f4(x + (size_t)row * N_FEAT + k4 * 4)
                             : make_float4(0.f, 0.f, 0.f, 0.f);
        *(float4*)&xs[r][k4 * 4] = v;
    }
    __syncthreads();
    int rr = t >> 4, f = t & 15;
    int row = row0 + rr;
    if (row >= N) return;
    float acc = 0.f;
#pragma unroll
    for (int k4 = 0; k4 < 32; ++k4) {
        float4 xv = *(const float4*)&xs[rr][k4 * 4];
        float4 wv = *(const float4*)&wsT[f][k4 * 4];
        acc += xv.x * wv.x + xv.y * wv.y + xv.z * wv.z + xv.w * wv.w;
    }
    float v = acc * dinv[row];
    if (f < FH) hsA[(size_t)row * FH + f] = v;
    else        hsB[(size_t)row * FH + (f - FH)] = v;
}

// ------- layer-1 aggregate, one feature-half: 8 lanes/node, 32B gathers -------
// hsH = 3.2 MB -> per-XCD L2-resident. Writes partial (h0,h1) per node.
__global__ __launch_bounds__(256) void agg1h_kernel(const int* __restrict__ rstart,
        const int* __restrict__ csr, const float* __restrict__ hsH,
        const float* __restrict__ dinv, const float* __restrict__ b1,
        const float* __restrict__ W2, float* __restrict__ part, int N, int f0) {
    int t = threadIdx.x;
    int g = blockIdx.x * 32 + (t >> 3);
    int f = t & 7;
    if (g >= N) return;
    int s = rstart[g], e = rstart[g + 1];
    float acc = hsH[(size_t)g * FH + f];   // self loop
    int k = s;
    for (; k + 4 <= e; k += 4) {
        int s0 = nt_load_i(&csr[k]);
        int s1 = nt_load_i(&csr[k + 1]);
        int s2 = nt_load_i(&csr[k + 2]);
        int s3 = nt_load_i(&csr[k + 3]);
        float v0 = hsH[(size_t)s0 * FH + f];
        float v1 = hsH[(size_t)s1 * FH + f];
        float v2 = hsH[(size_t)s2 * FH + f];
        float v3 = hsH[(size_t)s3 * FH + f];
        acc += (v0 + v1) + (v2 + v3);
    }
    for (; k < e; ++k) acc += hsH[(size_t)nt_load_i(&csr[k]) * FH + f];
    float di = dinv[g];
    float o = fmaxf(di * acc + b1[f0 + f], 0.f);
    float h0 = o * W2[(f0 + f) * F2 + 0];
    float h1 = o * W2[(f0 + f) * F2 + 1];
#pragma unroll
    for (int off = 1; off < 8; off <<= 1) {
        h0 += __shfl_xor(h0, off);
        h1 += __shfl_xor(h1, off);
    }
    if (f == 0) *(float2*)&part[(size_t)g * 2] = make_float2(h0, h1);
}

// ------- combine the two partial halves -> hs2 -------
__global__ void comb1_kernel(const float* __restrict__ p0, const float* __restrict__ p1,
        const float* __restrict__ dinv, float* __restrict__ hs2, int N) {
    int g = blockIdx.x * blockDim.x + threadIdx.x;
    if (g >= N) return;
    float2 a = *(const float2*)&p0[(size_t)g * 2];
    float2 b = *(const float2*)&p1[(size_t)g * 2];
    float di = dinv[g];
    *(float2*)&hs2[(size_t)g * 2] = make_float2(di * (a.x + b.x), di * (a.y + b.y));
}

// ------- layer-2 CSR gather + register accumulate + fused finalize -> out -------
__global__ __launch_bounds__(256) void agg2_kernel(const int* __restrict__ rstart,
        const int* __restrict__ csr, const float* __restrict__ hs2,
        const float* __restrict__ dinv, const float* __restrict__ b2,
        float* __restrict__ out, int N) {
    int t = threadIdx.x;
    int g = blockIdx.x * 64 + (t >> 2);
    int l = t & 3;
    if (g >= N) return;
    int j = l & 1, c = l >> 1;
    int s = rstart[g], e = rstart[g + 1];
    float acc = 0.f;
    int k = s + c;
    for (; k + 6 < e; k += 8) {
        int s0 = nt_load_i(&csr[k]);
        int s1 = nt_load_i(&csr[k + 2]);
        int s2 = nt_load_i(&csr[k + 4]);
        int s3 = nt_load_i(&csr[k + 6]);
        acc += hs2[(size_t)s0 * 2 + j] + hs2[(size_t)s1 * 2 + j]
             + hs2[(size_t)s2 * 2 + j] + hs2[(size_t)s3 * 2 + j];
    }
    for (; k < e; k += 2) acc += hs2[(size_t)nt_load_i(&csr[k]) * 2 + j];
    acc += __shfl_xor(acc, 2);
    if (l < 2)
        out[(size_t)g * 2 + j] = dinv[g] * (acc + hs2[(size_t)g * 2 + j]) + b2[j];
}

extern "C" void kernel_launch(void* const* d_in, const int* in_sizes, int n_in,
                              void* d_out, int out_size, void* d_ws, size_t ws_size,
                              hipStream_t stream) {
    const float* x  = (const float*)d_in[0];
    const int*   ei = (const int*)d_in[1];
    const float* W1 = (const float*)d_in[2];
    const float* b1 = (const float*)d_in[3];
    const float* W2 = (const float*)d_in[4];
    const float* b2 = (const float*)d_in[5];
    int N = in_sizes[0] / N_FEAT;
    int E = in_sizes[1] / 2;
    const int* rowi = ei;        // edge_index[0] = src
    const int* coli = ei + E;    // edge_index[1] = dst
    float* out = (float*)d_out;

    int nbuck = (N + NPB - 1) >> NPB_SHIFT;   // 196 for N=100000 (<= BMAX)

    // workspace layout (4B units)
    size_t NP = ((size_t)N + 1023) & ~(size_t)1023;
    size_t EP = ((size_t)E + 1023) & ~(size_t)1023;
    int*   wsI    = (int*)d_ws;
    float* dinv   = (float*)wsI;                       // NP
    int*   rstart = wsI + NP;                          // NP + 1024 (N+1 used)
    int*   bcnt   = wsI + 2 * NP + 1024;               // 512
    int*   bstart = wsI + 2 * NP + 1536;               // 512
    int*   gcur   = wsI + 2 * NP + 2048;               // 512 (+512 pad)
    float* hsA    = (float*)(wsI + 2 * NP + 3072);     // 8*NP
    float* hsB    = hsA + 8 * NP;                      // 8*NP
    float* hs2    = hsB + 8 * NP;                      // 2*NP
    float* p0     = hs2 + 2 * NP;                      // 2*NP
    float* p1     = p0 + 2 * NP;                       // 2*NP
    int*   ebin   = (int*)(p1 + 2 * NP);               // EP
    int*   csr    = ebin + EP;                         // EP
    int*   degp   = csr + EP;                          // K2*nbuck*NPB

    hipMemsetAsync(bcnt, 0, BMAX * sizeof(int), stream);

    hist_kernel<<<HBLK, 256, 0, stream>>>(coli, E, bcnt);
    bscan_kernel<<<1, BMAX, 0, stream>>>(bcnt, bstart, gcur, E, nbuck);
    bin_kernel<<<(E + CHUNK - 1) / CHUNK, 256, 0, stream>>>(rowi, coli, gcur, ebin, E);
    degpart_kernel<<<nbuck * K2, 256, 0, stream>>>(bstart, ebin, degp);
    rowscan_kernel<<<nbuck, 256, 0, stream>>>(bstart, degp, rstart, dinv, N, E);
    csrscat_kernel<<<nbuck * K2, 256, 0, stream>>>(bstart, rstart, degp, ebin, csr, N);
    gemm1_kernel<<<(N + 15) / 16, 256, 0, stream>>>(x, W1, dinv, hsA, hsB, N);

    // two sequential half-passes: 3.2 MB gather working set each (XCD-L2-resident)
    agg1h_kernel<<<(N + 31) / 32, 256, 0, stream>>>(rstart, csr, hsA, dinv, b1, W2, p0, N, 0);
    agg1h_kernel<<<(N + 31) / 32, 256, 0, stream>>>(rstart, csr, hsB, dinv, b1, W2, p1, N, FH);
    comb1_kernel<<<(N + 255) / 256, 256, 0, stream>>>(p0, p1, dinv, hs2, N);

    agg2_kernel<<<(N + 63) / 64, 256, 0, stream>>>(rstart, csr, hs2, dinv, b2, out, N);
}

// Round 11
// 301.386 us; speedup vs baseline: 1.1441x; 1.1441x over previous
//
#include <hip/hip_runtime.h>

#define N_FEAT 128
#define F1 16
#define F2 2
#define XPAD 132
#define NPB 512          // nodes per bucket (power of two)
#define NPB_SHIFT 9
#define BMAX 256         // max buckets -> supports N <= 131072
#define CHUNK 8192       // edges per binning block
#define HBLK 1024        // blocks for histogram kernel
#define K2 4             // slices per bucket (degree count: edge-slices; scatter: node-slices)

// ---- nontemporal helpers (builtin requires native/ext_vector types) ----
typedef int   ev_i4 __attribute__((ext_vector_type(4)));
typedef float ev_f4 __attribute__((ext_vector_type(4)));

__device__ __forceinline__ int4 nt_load_i4(const void* p) {
    ev_i4 v = __builtin_nontemporal_load((const ev_i4*)p);
    return make_int4(v.x, v.y, v.z, v.w);
}
__device__ __forceinline__ int nt_load_i(const int* p) {
    return __builtin_nontemporal_load(p);
}
__device__ __forceinline__ float4 nt_load_f4(const void* p) {
    ev_f4 v = __builtin_nontemporal_load((const ev_f4*)p);
    return make_float4(v.x, v.y, v.z, v.w);
}

// ---------------- bucket histogram only ----------------
__global__ __launch_bounds__(256) void hist_kernel(const int* __restrict__ col, int E,
        int* __restrict__ bcnt) {
    __shared__ int hist[BMAX];
    int t = threadIdx.x;
    hist[t] = 0;
    __syncthreads();
    int nq = (E + 3) >> 2;
    for (int q = blockIdx.x * 256 + t; q < nq; q += HBLK * 256) {
        int e0 = q * 4;
        if (e0 + 3 < E) {
            int4 c = nt_load_i4(col + e0);
            atomicAdd(&hist[c.x >> NPB_SHIFT], 1);
            atomicAdd(&hist[c.y >> NPB_SHIFT], 1);
            atomicAdd(&hist[c.z >> NPB_SHIFT], 1);
            atomicAdd(&hist[c.w >> NPB_SHIFT], 1);
        } else {
            for (int e = e0; e < E; ++e) atomicAdd(&hist[col[e] >> NPB_SHIFT], 1);
        }
    }
    __syncthreads();
    if (hist[t]) atomicAdd(&bcnt[t], hist[t]);
}

// ---------------- exclusive scan of bucket counts (single block) ----------------
__global__ __launch_bounds__(256) void bscan_kernel(const int* __restrict__ bcnt,
        int* __restrict__ bstart, int* __restrict__ gcur, int E, int nbuck) {
    __shared__ int s[BMAX];
    int t = threadIdx.x;
    int v = (t < nbuck) ? bcnt[t] : 0;
    s[t] = v;
    __syncthreads();
    for (int off = 1; off < BMAX; off <<= 1) {
        int a = (t >= off) ? s[t - off] : 0;
        __syncthreads();
        s[t] += a;
        __syncthreads();
    }
    int excl = s[t] - v;
    if (t < nbuck) { bstart[t] = excl; gcur[t] = excl; }
    if (t == 0) bstart[nbuck] = E;
}

// ---------------- bin edges into buckets, LDS-staged ----------------
// ebin word = (src << NPB_SHIFT) | (dst & (NPB-1)), grouped by bucket = dst >> NPB_SHIFT
__global__ __launch_bounds__(256) void bin_kernel(const int* __restrict__ rowi,
        const int* __restrict__ coli, int* __restrict__ gcur,
        int* __restrict__ ebin, int E) {
    __shared__ int stage[CHUNK];
    __shared__ unsigned char sbkt[CHUNK];
    __shared__ int cnt[BMAX];
    __shared__ int pos[BMAX];
    __shared__ int runb[BMAX];
    int t = threadIdx.x;
    int base = blockIdx.x * CHUNK;
    int nval = E - base; if (nval > CHUNK) nval = CHUNK;
    cnt[t] = 0;
    __syncthreads();

    int cbuf[32];
#pragma unroll
    for (int j = 0; j < 8; ++j) {
        int idx = base + ((j << 8) + t) * 4;
        if (idx + 3 < E) {
            int4 c4 = nt_load_i4(coli + idx);
            cbuf[j * 4 + 0] = c4.x; cbuf[j * 4 + 1] = c4.y;
            cbuf[j * 4 + 2] = c4.z; cbuf[j * 4 + 3] = c4.w;
        } else {
#pragma unroll
            for (int u = 0; u < 4; ++u) {
                int i2 = idx + u;
                cbuf[j * 4 + u] = (i2 < E) ? coli[i2] : -1;
            }
        }
    }
#pragma unroll
    for (int k = 0; k < 32; ++k)
        if (cbuf[k] >= 0) atomicAdd(&cnt[cbuf[k] >> NPB_SHIFT], 1);
    __syncthreads();

    pos[t] = cnt[t];
    __syncthreads();
    for (int off = 1; off < BMAX; off <<= 1) {
        int a = (t >= off) ? pos[t - off] : 0;
        __syncthreads();
        pos[t] += a;
        __syncthreads();
    }
    int myc = cnt[t];
    int excl = pos[t] - myc;
    if (myc > 0) {
        int g = atomicAdd(&gcur[t], myc);
        runb[t] = g - excl;
    }
    __syncthreads();
    cnt[t] = excl;
    __syncthreads();

#pragma unroll
    for (int j = 0; j < 8; ++j) {
        int idx = base + ((j << 8) + t) * 4;
        int rr[4];
        if (idx + 3 < E) {
            int4 r4 = nt_load_i4(rowi + idx);
            rr[0] = r4.x; rr[1] = r4.y; rr[2] = r4.z; rr[3] = r4.w;
        } else {
#pragma unroll
            for (int u = 0; u < 4; ++u) {
                int i2 = idx + u;
                rr[u] = (i2 < E) ? rowi[i2] : 0;
            }
        }
#pragma unroll
        for (int u = 0; u < 4; ++u) {
            int c = cbuf[j * 4 + u];
            if (c >= 0) {
                int b = c >> NPB_SHIFT;
                int lp = atomicAdd(&cnt[b], 1);
                stage[lp] = (rr[u] << NPB_SHIFT) | (c & (NPB - 1));
                sbkt[lp] = (unsigned char)b;
            }
        }
    }
    __syncthreads();
    // bucket-sorted, lane-consecutive write-out (plain stores: L2 write-combines)
    for (int i = t; i < nval; i += 256)
        ebin[runb[sbkt[i]] + i] = stage[i];
}

// ---------------- per-node degree from binned edges (edge-slices, 784 blocks) ----------------
__global__ __launch_bounds__(256) void degpart_kernel(const int* __restrict__ bstart,
        const int* __restrict__ ebin, int* __restrict__ degp) {
    __shared__ int cnt[NPB];
    int t = threadIdx.x;
    int bid = blockIdx.x;
    int b = bid / K2, slice = bid - b * K2;
    cnt[t] = 0; cnt[t + 256] = 0;
    __syncthreads();
    int s = bstart[b], e = bstart[b + 1];
    int per = (e - s + K2 - 1) / K2;
    int s0 = s + slice * per;
    int e0 = s0 + per; if (e0 > e) e0 = e;
    for (int i = s0 + t; i < e0; i += 1024) {
        int w[4];
#pragma unroll
        for (int u = 0; u < 4; ++u) {
            int idx = i + u * 256;
            w[u] = (idx < e0) ? nt_load_i(&ebin[idx]) : -1;
        }
#pragma unroll
        for (int u = 0; u < 4; ++u)
            if (w[u] >= 0) atomicAdd(&cnt[w[u] & (NPB - 1)], 1);
    }
    __syncthreads();
    int* dp = degp + (size_t)bid * NPB;
    dp[t] = cnt[t];
    dp[t + 256] = cnt[t + 256];
}

// ------- per-bucket: sum degree slices, LDS scan -> CSR row_start, dinv -------
__global__ __launch_bounds__(256) void rowscan_kernel(const int* __restrict__ bstart,
        const int* __restrict__ degp, int* __restrict__ rstart,
        float* __restrict__ dinv, int N, int E) {
    __shared__ int sd[NPB];
    int b = blockIdx.x, t = threadIdx.x;
    int base = b << NPB_SHIFT;
    int d0 = 0, d1 = 0;
    for (int sl = 0; sl < K2; ++sl) {
        const int* dp = degp + (size_t)(b * K2 + sl) * NPB;
        d0 += dp[t]; d1 += dp[t + 256];
    }
    sd[t] = d0; sd[t + 256] = d1;
    __syncthreads();
    for (int off = 1; off < NPB; off <<= 1) {
        int a0 = (t >= off) ? sd[t - off] : 0;
        int a1 = (t + 256 >= off) ? sd[t + 256 - off] : 0;
        __syncthreads();
        sd[t] += a0; sd[t + 256] += a1;
        __syncthreads();
    }
    int bs = bstart[b];
    int g0 = base + t, g1 = base + t + 256;
    if (g0 < N) { rstart[g0] = bs + sd[t] - d0;        dinv[g0] = rsqrtf((float)(d0 + 1)); }
    if (g1 < N) { rstart[g1] = bs + sd[t + 256] - d1;  dinv[g1] = rsqrtf((float)(d1 + 1)); }
    if (b == 0 && t == 0) rstart[N] = E;
}

// ------- CSR scatter, sliced by NODE-range: each node's run has a single writer block ----
// Block (b,q) re-reads bucket b's edges (plain loads: 3/4 are L2 hits) and scatters
// only nodes [q*128,(q+1)*128). No cross-block cache-line sharing on the write side.
__global__ __launch_bounds__(256) void nodescat_kernel(const int* __restrict__ bstart,
        const int* __restrict__ rstart, const int* __restrict__ ebin,
        int* __restrict__ csr, int N) {
    __shared__ int cur[128];
    int t = threadIdx.x;
    int bid = blockIdx.x;
    int b = bid >> 2, q = bid & 3;
    int lo = q << 7;
    if (t < 128) {
        int g = (b << NPB_SHIFT) + lo + t;
        cur[t] = (g < N) ? rstart[g] : 0;
    }
    __syncthreads();
    int s = bstart[b], e = bstart[b + 1];
    for (int i = s + t; i < e; i += 1024) {
        int w[4];
#pragma unroll
        for (int u = 0; u < 4; ++u) {
            int idx = i + u * 256;
            w[u] = (idx < e) ? ebin[idx] : -1;
        }
#pragma unroll
        for (int u = 0; u < 4; ++u) {
            if (w[u] >= 0) {
                int n = (w[u] & (NPB - 1)) - lo;
                if ((unsigned)n < 128u) {
                    int p = atomicAdd(&cur[n], 1);
                    csr[p] = w[u] >> NPB_SHIFT;
                }
            }
        }
    }
}

// ---------------- layer-1 GEMM: hs[r][f] = dinv[r] * sum_k x[r,k]*W1[k,f] ----------------
__global__ __launch_bounds__(256) void gemm1_kernel(
    const float* __restrict__ x, const float* __restrict__ W1,
    const float* __restrict__ dinv, float* __restrict__ hs, int N) {
    __shared__ __align__(16) float wsT[F1][XPAD];   // wsT[f][k] = W1[k][f]
    __shared__ __align__(16) float xs[16][XPAD];
    int t = threadIdx.x;
    for (int i = t; i < N_FEAT * F1; i += 256) {
        int k = i >> 4, f = i & 15;
        wsT[f][k] = W1[i];
    }
    int row0 = blockIdx.x * 16;
    for (int i = t; i < 16 * (N_FEAT / 4); i += 256) {
        int r = i >> 5, k4 = i & 31;
        int row = row0 + r;
        float4 v = (row < N) ? nt_load_f4(x + (size_t)row * N_FEAT + k4 * 4)
                             : make_float4(0.f, 0.f, 0.f, 0.f);
        *(float4*)&xs[r][k4 * 4] = v;
    }
    __syncthreads();
    int rr = t >> 4, f = t & 15;
    int row = row0 + rr;
    if (row >= N) return;
    float acc = 0.f;
#pragma unroll
    for (int k4 = 0; k4 < 32; ++k4) {
        float4 xv = *(const float4*)&xs[rr][k4 * 4];
        float4 wv = *(const float4*)&wsT[f][k4 * 4];
        acc += xv.x * wv.x + xv.y * wv.y + xv.z * wv.z + xv.w * wv.w;
    }
    hs[(size_t)row * F1 + f] = acc * dinv[row];
}

// ------- layer-1 CSR gather + register accumulate + fused bias/relu/W2 -> hs2 -------
// 16 lanes per node (lane = feature). hs gathers are 64B-coalesced per edge.
__global__ __launch_bounds__(256) void agg1_kernel(const int* __restrict__ rstart,
        const int* __restrict__ csr, const float* __restrict__ hs,
        const float* __restrict__ dinv, const float* __restrict__ b1,
        const float* __restrict__ W2, float* __restrict__ hs2, int N) {
    int t = threadIdx.x;
    int g = blockIdx.x * 16 + (t >> 4);
    int f = t & 15;
    if (g >= N) return;
    int s = rstart[g], e = rstart[g + 1];
    float acc = hs[(size_t)g * F1 + f];   // self loop
    int k = s;
    for (; k + 4 <= e; k += 4) {
        int s0 = nt_load_i(&csr[k]);
        int s1 = nt_load_i(&csr[k + 1]);
        int s2 = nt_load_i(&csr[k + 2]);
        int s3 = nt_load_i(&csr[k + 3]);
        float v0 = hs[(size_t)s0 * F1 + f];
        float v1 = hs[(size_t)s1 * F1 + f];
        float v2 = hs[(size_t)s2 * F1 + f];
        float v3 = hs[(size_t)s3 * F1 + f];
        acc += (v0 + v1) + (v2 + v3);
    }
    for (; k < e; ++k) acc += hs[(size_t)nt_load_i(&csr[k]) * F1 + f];
    float di = dinv[g];
    float o = fmaxf(di * acc + b1[f], 0.f);
    float h0 = o * W2[f * F2 + 0];
    float h1 = o * W2[f * F2 + 1];
#pragma unroll
    for (int off = 1; off < 16; off <<= 1) {
        h0 += __shfl_xor(h0, off);
        h1 += __shfl_xor(h1, off);
    }
    if (f == 0) *(float2*)&hs2[(size_t)g * 2] = make_float2(di * h0, di * h1);
}

// ------- layer-2 CSR gather + register accumulate + fused finalize -> out -------
__global__ __launch_bounds__(256) void agg2_kernel(const int* __restrict__ rstart,
        const int* __restrict__ csr, const float* __restrict__ hs2,
        const float* __restrict__ dinv, const float* __restrict__ b2,
        float* __restrict__ out, int N) {
    int t = threadIdx.x;
    int g = blockIdx.x * 64 + (t >> 2);
    int l = t & 3;
    if (g >= N) return;
    int j = l & 1, c = l >> 1;
    int s = rstart[g], e = rstart[g + 1];
    float acc = 0.f;
    int k = s + c;
    for (; k + 6 < e; k += 8) {
        int s0 = nt_load_i(&csr[k]);
        int s1 = nt_load_i(&csr[k + 2]);
        int s2 = nt_load_i(&csr[k + 4]);
        int s3 = nt_load_i(&csr[k + 6]);
        acc += hs2[(size_t)s0 * 2 + j] + hs2[(size_t)s1 * 2 + j]
             + hs2[(size_t)s2 * 2 + j] + hs2[(size_t)s3 * 2 + j];
    }
    for (; k < e; k += 2) acc += hs2[(size_t)nt_load_i(&csr[k]) * 2 + j];
    acc += __shfl_xor(acc, 2);
    if (l < 2)
        out[(size_t)g * 2 + j] = dinv[g] * (acc + hs2[(size_t)g * 2 + j]) + b2[j];
}

extern "C" void kernel_launch(void* const* d_in, const int* in_sizes, int n_in,
                              void* d_out, int out_size, void* d_ws, size_t ws_size,
                              hipStream_t stream) {
    const float* x  = (const float*)d_in[0];
    const int*   ei = (const int*)d_in[1];
    const float* W1 = (const float*)d_in[2];
    const float* b1 = (const float*)d_in[3];
    const float* W2 = (const float*)d_in[4];
    const float* b2 = (const float*)d_in[5];
    int N = in_sizes[0] / N_FEAT;
    int E = in_sizes[1] / 2;
    const int* rowi = ei;        // edge_index[0] = src
    const int* coli = ei + E;    // edge_index[1] = dst
    float* out = (float*)d_out;

    int nbuck = (N + NPB - 1) >> NPB_SHIFT;   // 196 for N=100000 (<= BMAX)

    // workspace layout (4B units)
    size_t NP = ((size_t)N + 1023) & ~(size_t)1023;
    size_t EP = ((size_t)E + 1023) & ~(size_t)1023;
    int*   wsI    = (int*)d_ws;
    float* dinv   = (float*)wsI;                       // NP
    int*   rstart = wsI + NP;                          // NP + 1024 (N+1 used)
    int*   bcnt   = wsI + 2 * NP + 1024;               // 512
    int*   bstart = wsI + 2 * NP + 1536;               // 512
    int*   gcur   = wsI + 2 * NP + 2048;               // 512 (+512 pad)
    float* hs     = (float*)(wsI + 2 * NP + 3072);     // 16*NP
    float* hs2    = hs + 16 * NP;                      // 2*NP
    int*   ebin   = (int*)(hs2 + 2 * NP);              // EP
    int*   csr    = ebin + EP;                         // EP
    int*   degp   = csr + EP;                          // K2*nbuck*NPB

    hipMemsetAsync(bcnt, 0, BMAX * sizeof(int), stream);

    hist_kernel<<<HBLK, 256, 0, stream>>>(coli, E, bcnt);
    bscan_kernel<<<1, BMAX, 0, stream>>>(bcnt, bstart, gcur, E, nbuck);
    bin_kernel<<<(E + CHUNK - 1) / CHUNK, 256, 0, stream>>>(rowi, coli, gcur, ebin, E);
    degpart_kernel<<<nbuck * K2, 256, 0, stream>>>(bstart, ebin, degp);
    rowscan_kernel<<<nbuck, 256, 0, stream>>>(bstart, degp, rstart, dinv, N, E);
    nodescat_kernel<<<nbuck * K2, 256, 0, stream>>>(bstart, rstart, ebin, csr, N);
    gemm1_kernel<<<(N + 15) / 16, 256, 0, stream>>>(x, W1, dinv, hs, N);

    agg1_kernel<<<(N + 15) / 16, 256, 0, stream>>>(rstart, csr, hs, dinv, b1, W2, hs2, N);
    agg2_kernel<<<(N + 63) / 64, 256, 0, stream>>>(rstart, csr, hs2, dinv, b2, out, N);
}